// Round 3
// baseline (999.674 us; speedup 1.0000x reference)
//
#include <hip/hip_runtime.h>
#include <hip/hip_bf16.h>
#include <math.h>

#define TOK 4096
#define HD 1024
#define FD 4096
#define NE 8

typedef __attribute__((ext_vector_type(4))) float f32x4;
typedef __attribute__((ext_vector_type(8))) short s16x8;
typedef __attribute__((ext_vector_type(4))) unsigned short u16x4;

typedef const __attribute__((address_space(1))) void g_void;
typedef __attribute__((address_space(3))) void lds_void;

__device__ __forceinline__ unsigned short f2bf(float f) {
    union { float f; unsigned u; } v; v.f = f;
    unsigned r = v.u + 0x7FFFu + ((v.u >> 16) & 1u);   // RNE
    return (unsigned short)(r >> 16);
}

// ---------------- router: sigmoid(x@Wr+br), top-1, compact lists, cast x->bf16
__global__ void router_kernel(const float* __restrict__ x, const float* __restrict__ Wr,
                              const float* __restrict__ br, int* __restrict__ counts,
                              int* __restrict__ tlist, float* __restrict__ mprob,
                              unsigned short* __restrict__ xb) {
    const int lane = threadIdx.x & 63;
    const int t = blockIdx.x * 4 + (threadIdx.x >> 6);
    const float* xr = x + (size_t)t * HD;
    unsigned short* xbr = xb + (size_t)t * HD;
    float acc[NE];
#pragma unroll
    for (int e = 0; e < NE; ++e) acc[e] = 0.f;
    for (int h = lane; h < HD; h += 64) {
        float xv = xr[h];
        xbr[h] = f2bf(xv);                          // coalesced bf16 cast-out
        f32x4 w0 = *(const f32x4*)(Wr + h * NE);
        f32x4 w1 = *(const f32x4*)(Wr + h * NE + 4);
        acc[0] += xv * w0.x; acc[1] += xv * w0.y; acc[2] += xv * w0.z; acc[3] += xv * w0.w;
        acc[4] += xv * w1.x; acc[5] += xv * w1.y; acc[6] += xv * w1.z; acc[7] += xv * w1.w;
    }
#pragma unroll
    for (int off = 32; off >= 1; off >>= 1)
#pragma unroll
        for (int e = 0; e < NE; ++e) acc[e] += __shfl_down(acc[e], off, 64);
    if (lane == 0) {
        float best = -1.f; int bi = 0;
#pragma unroll
        for (int e = 0; e < NE; ++e) {
            float r = 1.f / (1.f + expf(-(acc[e] + br[e])));
            if (r > best) { best = r; bi = e; }   // strict > keeps first index on tie
        }
        mprob[t] = best;
        int pos = atomicAdd(&counts[bi], 1);
        tlist[bi * TOK + pos] = t;
    }
}

// ---------------- weight transpose+cast: src [E][K][N] fp32 -> dst [E][N][K] bf16
template<int K, int N>
__global__ __launch_bounds__(256)
void transpose_cast(const float* __restrict__ src, unsigned short* __restrict__ dst) {
    __shared__ unsigned short T[64][72];
    const int e = blockIdx.z;
    const int n0 = blockIdx.x * 64;
    const int k0 = blockIdx.y * 64;
    const int tid = threadIdx.x;
    // load 64x64 fp32 tile coalesced, cast to bf16 into LDS
    {
        int c4 = (tid & 15) << 2;
#pragma unroll
        for (int it = 0; it < 4; ++it) {
            int r = (tid >> 4) + it * 16;
            f32x4 v = *(const f32x4*)(src + ((size_t)e * K + k0 + r) * N + n0 + c4);
            u16x4 p; p.x = f2bf(v.x); p.y = f2bf(v.y); p.z = f2bf(v.z); p.w = f2bf(v.w);
            *(u16x4*)&T[r][c4] = p;
        }
    }
    __syncthreads();
    // write transposed rows (n-major, k contiguous) with 16B stores
    {
        int c = tid >> 2;         // output row (n)
        int q = tid & 3;          // 16-elem quarter along k
        s16x8 v0, v1;
#pragma unroll
        for (int j = 0; j < 8; ++j) { v0[j] = (short)T[q * 16 + j][c]; v1[j] = (short)T[q * 16 + 8 + j][c]; }
        unsigned short* op = dst + ((size_t)e * N + n0 + c) * K + k0 + q * 16;
        *(s16x8*)op = v0;
        *(s16x8*)(op + 8) = v1;
    }
}

// ---------------- gathered expert GEMM (128x128 tile, 16x16x32 bf16 MFMA) ------
// m97-style LINEAR LDS layout: Al/Bl are [row][64 k-elems] row-major, 128B rows.
// Staging is strictly lane-linear global_load_lds (lane i -> i-th 16B of the
// tile) -- round 2's rotated-lane variant serialized the TA (307us, MfmaUtil
// 4.6%). Fragment ds_reads are 128B-strided across lanes (bank conflicts),
// which m98 measured as affordable (874 TF with 1.7e7 conflicts).
template<int K, bool FC1>
__global__ __launch_bounds__(256, 3)
void expert_gemm(const unsigned short* __restrict__ Asrc, const unsigned short* __restrict__ Wt,
                 const int* __restrict__ counts, const int* __restrict__ tlist,
                 const float* __restrict__ mprob,
                 unsigned short* __restrict__ inter, float* __restrict__ out) {
    constexpr int NDIM = FC1 ? FD : HD;
    const int e = blockIdx.z;
    const int cnt = counts[e];
    const int m0 = blockIdx.x * 128;
    if (m0 >= cnt) return;
    const int n0 = blockIdx.y * 128;

    __shared__ unsigned short Al[128 * 64];
    __shared__ unsigned short Bl[128 * 64];
    __shared__ int s_tok[128];
    __shared__ float s_prob[128];

    const int tid = threadIdx.x;
    if (tid < 128) {
        int m = m0 + tid;
        int tk = (m < cnt) ? tlist[e * TOK + m] : -1;
        s_tok[tid] = tk;
        s_prob[tid] = (!FC1 && tk >= 0) ? mprob[tk] : 0.f;
    }

    const int lane = tid & 63;
    const int wave = tid >> 6;
    // staging: wave w, inst it covers LDS elems [w*2048 + it*512, +512)
    // lane covers 8 elems at +lane*8 -> row r = w*32 + it*8 + (lane>>3),
    // k-chunk g = lane&7 (lane-linear: LDS byte off == 16*lane within inst)
    const unsigned short* aptr[4];
    const unsigned short* bptr[4];
    {
        int lr = lane >> 3, g = lane & 7;
#pragma unroll
        for (int it = 0; it < 4; ++it) {
            int r = wave * 32 + it * 8 + lr;
            int m = m0 + r;
            int tk = (m < cnt) ? tlist[e * TOK + m] : 0;  // clamp: row discarded in epilogue
            aptr[it] = Asrc + (size_t)tk * K + g * 8;
            bptr[it] = Wt + ((size_t)e * NDIM + n0 + r) * K + g * 8;
        }
    }

    const int wrow = (wave >> 1) << 6;
    const int wcol = (wave & 1) << 6;
    const int lm = lane & 15, quad = lane >> 4;

    f32x4 acc[4][4] = {};

    for (int k0 = 0; k0 < K; k0 += 64) {
        __syncthreads();   // previous iter's readers done (also covers s_tok prologue)
#pragma unroll
        for (int it = 0; it < 4; ++it) {
            __builtin_amdgcn_global_load_lds((g_void*)aptr[it],
                (lds_void*)&Al[wave * 2048 + it * 512], 16, 0, 0);
            __builtin_amdgcn_global_load_lds((g_void*)bptr[it],
                (lds_void*)&Bl[wave * 2048 + it * 512], 16, 0, 0);
            aptr[it] += 64; bptr[it] += 64;
        }
        __syncthreads();   // drains vmcnt -> tiles ready
#pragma unroll
        for (int kt = 0; kt < 2; ++kt) {
            s16x8 af[4], bf[4];
            int gk = (kt << 2) + quad;
#pragma unroll
            for (int mt = 0; mt < 4; ++mt) {
                int m = wrow + (mt << 4) + lm;
                af[mt] = *(const s16x8*)&Al[(m << 6) + (gk << 3)];
            }
#pragma unroll
            for (int nt = 0; nt < 4; ++nt) {
                int n = wcol + (nt << 4) + lm;
                bf[nt] = *(const s16x8*)&Bl[(n << 6) + (gk << 3)];
            }
#pragma unroll
            for (int mt = 0; mt < 4; ++mt)
#pragma unroll
                for (int nt = 0; nt < 4; ++nt)
                    acc[mt][nt] = __builtin_amdgcn_mfma_f32_16x16x32_bf16(
                        af[mt], bf[nt], acc[mt][nt], 0, 0, 0);
        }
    }

    // epilogue: C/D layout col=lane&15, row=quad*4+reg
#pragma unroll
    for (int mt = 0; mt < 4; ++mt) {
#pragma unroll
        for (int r = 0; r < 4; ++r) {
            int row = wrow + (mt << 4) + (quad << 2) + r;
            if (m0 + row >= cnt) continue;
            int tk = s_tok[row];
            int colb = n0 + wcol + lm;
            if constexpr (FC1) {
#pragma unroll
                for (int nt = 0; nt < 4; ++nt) {
                    float v = acc[mt][nt][r];
                    float g = 0.5f * v * (1.f + erff(v * 0.70710678f));  // exact gelu
                    inter[(size_t)tk * FD + colb + (nt << 4)] = f2bf(g);
                }
            } else {
                float p = s_prob[row];
#pragma unroll
                for (int nt = 0; nt < 4; ++nt)
                    out[(size_t)tk * HD + colb + (nt << 4)] = acc[mt][nt][r] * p;
            }
        }
    }
}

extern "C" void kernel_launch(void* const* d_in, const int* in_sizes, int n_in,
                              void* d_out, int out_size, void* d_ws, size_t ws_size,
                              hipStream_t stream) {
    const float* x  = (const float*)d_in[0];
    const float* Wr = (const float*)d_in[1];
    const float* br = (const float*)d_in[2];
    const float* W1 = (const float*)d_in[3];
    const float* W2 = (const float*)d_in[4];
    float* out = (float*)d_out;

    char* ws = (char*)d_ws;
    int* counts           = (int*)ws;                           // 32 B (pad 256)
    float* mprob          = (float*)(ws + 256);                 // 16 KB
    int* tlist            = (int*)(ws + 16640);                 // 128 KB
    unsigned short* xb    = (unsigned short*)(ws + 147712);     // TOK*HD bf16, 8 MB
    unsigned short* inter = (unsigned short*)(ws + 8536320);    // TOK*FD bf16, 32 MB
    unsigned short* Wt    = (unsigned short*)(ws + 42090752);   // 8*4096*1024 bf16, 64 MB (shared W1t/W2t)

    hipMemsetAsync(counts, 0, NE * sizeof(int), stream);
    router_kernel<<<TOK / 4, 256, 0, stream>>>(x, Wr, br, counts, tlist, mprob, xb);

    // W1 [E][HD][FD] -> Wt [E][FD][HD] bf16
    transpose_cast<HD, FD><<<dim3(FD / 64, HD / 64, NE), 256, 0, stream>>>(W1, Wt);
    // fc1: gelu(x @ W1) -> inter (bf16)
    expert_gemm<HD, true><<<dim3(TOK / 128, FD / 128, NE), 256, 0, stream>>>(
        xb, Wt, counts, tlist, mprob, inter, nullptr);

    // W2 [E][FD][HD] -> Wt [E][HD][FD] bf16 (reuse buffer; stream serializes)
    transpose_cast<FD, HD><<<dim3(HD / 64, FD / 64, NE), 256, 0, stream>>>(W2, Wt);
    // fc2: (inter @ W2) * max_prob -> out (fp32)
    expert_gemm<FD, false><<<dim3(TOK / 128, HD / 128, NE), 256, 0, stream>>>(
        inter, Wt, counts, tlist, mprob, nullptr, out);
}

// Round 4
// 619.599 us; speedup vs baseline: 1.6134x; 1.6134x over previous
//
#include <hip/hip_runtime.h>
#include <hip/hip_bf16.h>
#include <math.h>

#define TOK 4096
#define HD 1024
#define FD 4096
#define NE 8

typedef __attribute__((ext_vector_type(4))) float f32x4;
typedef __attribute__((ext_vector_type(8))) short s16x8;
typedef __attribute__((ext_vector_type(4))) unsigned short u16x4;

typedef const __attribute__((address_space(1))) void g_void;
typedef __attribute__((address_space(3))) void lds_void;

__device__ __forceinline__ unsigned short f2bf(float f) {
    union { float f; unsigned u; } v; v.f = f;
    unsigned r = v.u + 0x7FFFu + ((v.u >> 16) & 1u);   // RNE
    return (unsigned short)(r >> 16);
}

// ---------------- router: sigmoid(x@Wr+br), top-1, compact lists, cast x->bf16
__global__ void router_kernel(const float* __restrict__ x, const float* __restrict__ Wr,
                              const float* __restrict__ br, int* __restrict__ counts,
                              int* __restrict__ tlist, float* __restrict__ mprob,
                              unsigned short* __restrict__ xb) {
    const int lane = threadIdx.x & 63;
    const int t = blockIdx.x * 4 + (threadIdx.x >> 6);
    const float* xr = x + (size_t)t * HD;
    unsigned short* xbr = xb + (size_t)t * HD;
    float acc[NE];
#pragma unroll
    for (int e = 0; e < NE; ++e) acc[e] = 0.f;
    for (int h = lane; h < HD; h += 64) {
        float xv = xr[h];
        xbr[h] = f2bf(xv);                          // coalesced bf16 cast-out
        f32x4 w0 = *(const f32x4*)(Wr + h * NE);
        f32x4 w1 = *(const f32x4*)(Wr + h * NE + 4);
        acc[0] += xv * w0.x; acc[1] += xv * w0.y; acc[2] += xv * w0.z; acc[3] += xv * w0.w;
        acc[4] += xv * w1.x; acc[5] += xv * w1.y; acc[6] += xv * w1.z; acc[7] += xv * w1.w;
    }
#pragma unroll
    for (int off = 32; off >= 1; off >>= 1)
#pragma unroll
        for (int e = 0; e < NE; ++e) acc[e] += __shfl_down(acc[e], off, 64);
    if (lane == 0) {
        float best = -1.f; int bi = 0;
#pragma unroll
        for (int e = 0; e < NE; ++e) {
            float r = 1.f / (1.f + expf(-(acc[e] + br[e])));
            if (r > best) { best = r; bi = e; }   // strict > keeps first index on tie
        }
        mprob[t] = best;
        int pos = atomicAdd(&counts[bi], 1);
        tlist[bi * TOK + pos] = t;
    }
}

// ---------------- weight transpose+cast: src [E][K][N] fp32 -> dst [E][N][K] bf16
template<int K, int N>
__global__ __launch_bounds__(256)
void transpose_cast(const float* __restrict__ src, unsigned short* __restrict__ dst) {
    __shared__ unsigned short T[64][72];
    const int e = blockIdx.z;
    const int n0 = blockIdx.x * 64;
    const int k0 = blockIdx.y * 64;
    const int tid = threadIdx.x;
    {
        int c4 = (tid & 15) << 2;
#pragma unroll
        for (int it = 0; it < 4; ++it) {
            int r = (tid >> 4) + it * 16;
            f32x4 v = *(const f32x4*)(src + ((size_t)e * K + k0 + r) * N + n0 + c4);
            u16x4 p; p.x = f2bf(v.x); p.y = f2bf(v.y); p.z = f2bf(v.z); p.w = f2bf(v.w);
            *(u16x4*)&T[r][c4] = p;
        }
    }
    __syncthreads();
    {
        int c = tid >> 2;         // output row (n)
        int q = tid & 3;          // 16-elem quarter along k
        s16x8 v0, v1;
#pragma unroll
        for (int j = 0; j < 8; ++j) { v0[j] = (short)T[q * 16 + j][c]; v1[j] = (short)T[q * 16 + 8 + j][c]; }
        unsigned short* op = dst + ((size_t)e * N + n0 + c) * K + k0 + q * 16;
        *(s16x8*)op = v0;
        *(s16x8*)(op + 8) = v1;
    }
}

// ---------------- gathered expert GEMM (128x128 tile, 16x16x32 bf16 MFMA) ------
// GRID: blockIdx.x = N-blocks (ALL active) so linear block ids of live blocks
// cover all residues mod 8 -> uniform XCD spread. Rounds 2-3 had x = M-blocks
// (only 0..3 of 32 live) -> every live block landed on XCDs 0-3 (occupancy 4.5%).
// LDS: round-2 swizzled-global layout, slot (r,g) holds k-group (g-r)&7 of row r
// (measured SQ_LDS_BANK_CONFLICT == 0). Staging = lane-linear global_load_lds x16.
template<int K, bool FC1, int KSPLIT>
__global__ __launch_bounds__(256, 4)
void expert_gemm(const unsigned short* __restrict__ Asrc, const unsigned short* __restrict__ Wt,
                 const int* __restrict__ counts, const int* __restrict__ tlist,
                 const float* __restrict__ mprob,
                 unsigned short* __restrict__ inter, float* __restrict__ out) {
    constexpr int NDIM = FC1 ? FD : HD;
    constexpr int KC = K / KSPLIT;
    const int e  = (KSPLIT == 1) ? blockIdx.z : (blockIdx.z & (NE - 1));
    const int ks = (KSPLIT == 1) ? 0 : ((int)blockIdx.z >> 3);
    const int kbase = ks * KC;
    const int cnt = counts[e];
    const int m0 = blockIdx.y * 128;
    if (m0 >= cnt) return;
    const int n0 = blockIdx.x * 128;

    __shared__ unsigned short Al[128 * 64];
    __shared__ unsigned short Bl[128 * 64];
    __shared__ int s_tok[128];
    __shared__ float s_prob[128];

    const int tid = threadIdx.x;
    if (tid < 128) {
        int m = m0 + tid;
        int tk = (m < cnt) ? tlist[e * TOK + m] : -1;
        s_tok[tid] = tk;
        s_prob[tid] = (!FC1 && tk >= 0) ? mprob[tk] : 0.f;
    }

    const int lane = tid & 63;
    const int wave = tid >> 6;
    // swizzled-global staging: lane (lr,g) feeds LDS slot g of row r; the slot
    // holds k-group kg=(g-r)&7 so fragment reads are conflict-free.
    const unsigned short* aptr[4];
    const unsigned short* bptr[4];
    {
        int lr = lane >> 3, g = lane & 7;
#pragma unroll
        for (int it = 0; it < 4; ++it) {
            int r = wave * 32 + it * 8 + lr;
            int kg = (g - r) & 7;
            int m = m0 + r;
            int tk = (m < cnt) ? tlist[e * TOK + m] : 0;  // clamp: row discarded in epilogue
            aptr[it] = Asrc + (size_t)tk * K + kbase + kg * 8;
            bptr[it] = Wt + ((size_t)e * NDIM + n0 + r) * K + kbase + kg * 8;
        }
    }

    const int wrow = (wave >> 1) << 6;
    const int wcol = (wave & 1) << 6;
    const int lm = lane & 15, quad = lane >> 4;

    f32x4 acc[4][4] = {};

    for (int k0 = 0; k0 < KC; k0 += 64) {
        __syncthreads();   // prev iter's readers done (also covers s_tok prologue)
#pragma unroll
        for (int it = 0; it < 4; ++it) {
            __builtin_amdgcn_global_load_lds((g_void*)aptr[it],
                (lds_void*)&Al[wave * 2048 + it * 512], 16, 0, 0);
            __builtin_amdgcn_global_load_lds((g_void*)bptr[it],
                (lds_void*)&Bl[wave * 2048 + it * 512], 16, 0, 0);
            aptr[it] += 64; bptr[it] += 64;
        }
        __syncthreads();   // drains vmcnt -> tiles ready
#pragma unroll
        for (int kt = 0; kt < 2; ++kt) {
            s16x8 af[4], bf[4];
            int gk = (kt << 2) + quad;
#pragma unroll
            for (int mt = 0; mt < 4; ++mt) {
                int m = wrow + (mt << 4) + lm;
                af[mt] = *(const s16x8*)&Al[(m << 6) + (((gk + m) & 7) << 3)];
            }
#pragma unroll
            for (int nt = 0; nt < 4; ++nt) {
                int n = wcol + (nt << 4) + lm;
                bf[nt] = *(const s16x8*)&Bl[(n << 6) + (((gk + n) & 7) << 3)];
            }
#pragma unroll
            for (int mt = 0; mt < 4; ++mt)
#pragma unroll
                for (int nt = 0; nt < 4; ++nt)
                    acc[mt][nt] = __builtin_amdgcn_mfma_f32_16x16x32_bf16(
                        af[mt], bf[nt], acc[mt][nt], 0, 0, 0);
        }
    }

    // epilogue: C/D layout col=lane&15, row=quad*4+reg
#pragma unroll
    for (int mt = 0; mt < 4; ++mt) {
#pragma unroll
        for (int r = 0; r < 4; ++r) {
            int row = wrow + (mt << 4) + (quad << 2) + r;
            if (m0 + row >= cnt) continue;
            int tk = s_tok[row];
            int colb = n0 + wcol + lm;
            if constexpr (FC1) {
#pragma unroll
                for (int nt = 0; nt < 4; ++nt) {
                    float v = acc[mt][nt][r];
                    float g = 0.5f * v * (1.f + erff(v * 0.70710678f));  // exact gelu
                    inter[(size_t)tk * FD + colb + (nt << 4)] = f2bf(g);
                }
            } else {
                float p = s_prob[row];
#pragma unroll
                for (int nt = 0; nt < 4; ++nt)
                    atomicAdd(&out[(size_t)tk * HD + colb + (nt << 4)], acc[mt][nt][r] * p);
            }
        }
    }
}

extern "C" void kernel_launch(void* const* d_in, const int* in_sizes, int n_in,
                              void* d_out, int out_size, void* d_ws, size_t ws_size,
                              hipStream_t stream) {
    const float* x  = (const float*)d_in[0];
    const float* Wr = (const float*)d_in[1];
    const float* br = (const float*)d_in[2];
    const float* W1 = (const float*)d_in[3];
    const float* W2 = (const float*)d_in[4];
    float* out = (float*)d_out;

    char* ws = (char*)d_ws;
    int* counts           = (int*)ws;                           // 32 B (pad 256)
    float* mprob          = (float*)(ws + 256);                 // 16 KB
    int* tlist            = (int*)(ws + 16640);                 // 128 KB
    unsigned short* xb    = (unsigned short*)(ws + 147712);     // TOK*HD bf16, 8 MB
    unsigned short* inter = (unsigned short*)(ws + 8536320);    // TOK*FD bf16, 32 MB
    unsigned short* Wt    = (unsigned short*)(ws + 42090752);   // 8*4096*1024 bf16, 64 MB (shared W1t/W2t)

    hipMemsetAsync(counts, 0, NE * sizeof(int), stream);
    hipMemsetAsync(out, 0, (size_t)out_size * sizeof(float), stream);  // split-K accumulates
    router_kernel<<<TOK / 4, 256, 0, stream>>>(x, Wr, br, counts, tlist, mprob, xb);

    // W1 [E][HD][FD] -> Wt [E][FD][HD] bf16
    transpose_cast<HD, FD><<<dim3(FD / 64, HD / 64, NE), 256, 0, stream>>>(W1, Wt);
    // fc1: gelu(x @ W1) -> inter (bf16).  x = N-blocks (all active -> XCD spread)
    expert_gemm<HD, true, 1><<<dim3(FD / 128, TOK / 128, NE), 256, 0, stream>>>(
        xb, Wt, counts, tlist, mprob, inter, nullptr);

    // W2 [E][FD][HD] -> Wt [E][HD][FD] bf16 (reuse buffer; stream serializes)
    transpose_cast<FD, HD><<<dim3(HD / 64, FD / 64, NE), 256, 0, stream>>>(W2, Wt);
    // fc2: (inter @ W2) * max_prob -> out (fp32), split-K=4, atomic accumulate
    expert_gemm<FD, false, 4><<<dim3(HD / 128, TOK / 128, NE * 4), 256, 0, stream>>>(
        inter, Wt, counts, tlist, mprob, nullptr, out);
}